// Round 16
// baseline (1097.989 us; speedup 1.0000x reference)
//
#include <hip/hip_runtime.h>
#include <hip/hip_bf16.h>

#define B_   4
#define DENC 512
#define T_   200
#define DDEC 640
#define U_   100
#define H_   640
#define V_   1025
#define VPAD 1152

typedef float f32x4 __attribute__((ext_vector_type(4)));
typedef __bf16 bf16x8 __attribute__((ext_vector_type(8)));
typedef unsigned short u16x8 __attribute__((ext_vector_type(8)));

__device__ __forceinline__ float bf2f(unsigned short s) {
    return __uint_as_float(((unsigned)s) << 16);
}

__device__ __forceinline__ unsigned addrelu_pk(unsigned e, unsigned d) {
    float elo = __uint_as_float(e << 16);
    float ehi = __uint_as_float(e & 0xffff0000u);
    float dlo = __uint_as_float(d << 16);
    float dhi = __uint_as_float(d & 0xffff0000u);
    float lo = fmaxf(elo + dlo, 0.f);
    float hi = fmaxf(ehi + dhi, 0.f);
    unsigned r;
    asm("v_cvt_pk_bf16_f32 %0, %1, %2" : "=v"(r) : "v"(lo), "v"(hi));
    return r;
}

__device__ __forceinline__ void gload_lds16(const void* g, void* l) {
    __builtin_amdgcn_global_load_lds(
        (const __attribute__((address_space(1))) unsigned int*)g,
        (__attribute__((address_space(3))) unsigned int*)l, 16, 0, 0);
}

// ---------------- K1: fused prep (r13-proven): enc_proj | dec_proj | wt_transpose
__global__ __launch_bounds__(256) void prep_fused_kernel(
    const float* __restrict__ enc, const float* __restrict__ W_enc,
    const float* __restrict__ b_enc,
    const float* __restrict__ dec, const float* __restrict__ W_pred,
    const float* __restrict__ b_pred,
    const float* __restrict__ W_out,
    __hip_bfloat16* __restrict__ encP, __hip_bfloat16* __restrict__ decP,
    unsigned short* __restrict__ Wt)
{
    __shared__ float tile[64][65];
    int bx = blockIdx.x;
    int tid = threadIdx.x;

    if (bx < 260) {
        int b = bx / 65, r5 = bx % 65, hc = r5 / 13, tg = r5 % 13;
        int h  = hc * 128 + (tid & 127);
        int t0 = tg * 16 + (tid >> 7) * 8;
        if (t0 >= T_) return;
        const float* ec = enc + (size_t)b * DENC * T_ + t0;
        const float* Wc = W_enc + h;
        float acc[8] = {0.f,0.f,0.f,0.f,0.f,0.f,0.f,0.f};
        #pragma unroll 8
        for (int d = 0; d < DENC; ++d) {
            float w = Wc[(size_t)d * H_];
            float4 e0 = *(const float4*)(ec + (size_t)d * T_);
            float4 e1 = *(const float4*)(ec + (size_t)d * T_ + 4);
            acc[0] += w * e0.x; acc[1] += w * e0.y; acc[2] += w * e0.z; acc[3] += w * e0.w;
            acc[4] += w * e1.x; acc[5] += w * e1.y; acc[6] += w * e1.z; acc[7] += w * e1.w;
        }
        float bb = b_enc[h];
        #pragma unroll
        for (int i = 0; i < 8; ++i)
            encP[((size_t)b * T_ + t0 + i) * H_ + h] = __float2bfloat16(acc[i] + bb);
    } else if (bx < 520) {
        int i5 = bx - 260;
        int b = i5 / 65, r5 = i5 % 65, hc = r5 / 13, ug = r5 % 13;
        int h  = hc * 128 + (tid & 127);
        int u0 = ug * 8 + (tid >> 7) * 4;
        if (u0 >= U_) return;
        const float* dc = dec + (size_t)b * DDEC * U_ + u0;
        const float* Wc = W_pred + h;
        float acc[4] = {0.f,0.f,0.f,0.f};
        #pragma unroll 8
        for (int d = 0; d < DDEC; ++d) {
            float w = Wc[(size_t)d * H_];
            float4 e0 = *(const float4*)(dc + (size_t)d * U_);
            acc[0] += w * e0.x; acc[1] += w * e0.y; acc[2] += w * e0.z; acc[3] += w * e0.w;
        }
        float bb = b_pred[h];
        #pragma unroll
        for (int i = 0; i < 4; ++i)
            decP[((size_t)b * U_ + u0 + i) * H_ + h] = __float2bfloat16(acc[i] + bb);
    } else {
        int j = bx - 520;
        int hc = j / 18, vc = j % 18;
        int h0 = hc * 64, v0 = vc * 64;
        #pragma unroll
        for (int it = 0; it < 16; ++it) {
            int hl = it * 4 + (tid >> 6);
            int vl = tid & 63;
            int v = v0 + vl;
            tile[hl][vl] = (v < V_) ? W_out[(size_t)(h0 + hl) * V_ + v] : 0.f;
        }
        __syncthreads();
        #pragma unroll
        for (int it = 0; it < 16; ++it) {
            int vl = it * 4 + (tid >> 6);
            int hl = tid & 63;
            __bf16 bv = (__bf16)tile[hl][vl];
            Wt[(size_t)(v0 + vl) * H_ + h0 + hl] = *(unsigned short*)&bv;
        }
    }
}

// ---------------- K4: r8-proven joint + LDS-transpose epilogue with SCALAR
// lane-contiguous stores (one instr = one 256B contiguous chunk; L2 merges the row).
// blocks [0,5200): GEMM tiles (XCD-swizzled).  blocks [5200,5513): v=1024 column.
#define ESTR 260   // epilogue LDS stride (f32): 2 lanes/bank both phases (free)
__global__ __launch_bounds__(256) void joint_kernel(
    const unsigned short* __restrict__ encP,   // [B,T,H] bf16
    const unsigned short* __restrict__ decP,   // [B,U,H] bf16
    const unsigned short* __restrict__ Wt,     // [VPAD][H] bf16
    const float* __restrict__ b_out,           // [V]
    float* __restrict__ out)                   // [B,T,U,V] f32
{
    __shared__ uint4 LA[2][64][4];             // 8 KB
    __shared__ uint4 LB[2][256][4];            // 32 KB
    int tid = threadIdx.x;

    if (blockIdx.x >= 5200) {
        // ---- fused lastcol: v = 1024
        int idx = (blockIdx.x - 5200) * 256 + tid;
        if (idx >= B_ * T_ * U_) return;
        int u = idx % U_;
        int t = (idx / U_) % T_;
        int b = idx / (U_ * T_);
        const u16x8* e = (const u16x8*)(encP + ((size_t)b * T_ + t) * H_);
        const u16x8* d = (const u16x8*)(decP + ((size_t)b * U_ + u) * H_);
        const u16x8* wv = (const u16x8*)(Wt + (size_t)1024 * H_);
        float acc1 = 0.f;
        for (int c = 0; c < H_ / 8; ++c) {
            u16x8 ev = e[c], dv = d[c], wq = wv[c];
            #pragma unroll
            for (int m = 0; m < 8; ++m)
                acc1 += fmaxf(bf2f(ev[m]) + bf2f(dv[m]), 0.f) * bf2f(wq[m]);
        }
        out[((size_t)(b * T_ + t) * U_ + u) * V_ + 1024] = acc1 + b_out[1024];
        return;
    }

    // ---- XCD swizzle over the 5200 GEMM blocks: f -> n = (f&7)*650 + (f>>3)
    int f   = blockIdx.x;
    int n   = (f & 7) * 650 + (f >> 3);
    int vi  = n / 1300;
    int rem = n - vi * 1300;
    int b   = rem / 325;
    int tu  = rem - b * 325;

    int tt = tu / 13, ut = tu % 13;
    int t0 = tt * 8, u0 = ut * 8, vb = vi * 256;
    int lane = tid & 63, w = tid >> 6;
    int lrow = lane & 15, kg = lane >> 4;

    int r  = tid >> 2, kc = tid & 3;
    int ta = t0 + (r >> 3);
    int ua = u0 + (r & 7); if (ua > U_ - 1) ua = U_ - 1;
    const unsigned short* eR = encP + ((size_t)b * T_ + ta) * H_ + kc * 8;
    const unsigned short* dR = decP + ((size_t)b * U_ + ua) * H_ + kc * 8;
    int fA = (r >> 1) & 3;

    int pcB = lane & 3;
    const unsigned short* gB[4];
    #pragma unroll
    for (int m = 0; m < 4; ++m) {
        int cl = w * 64 + m * 16 + (lane >> 2);
        gB[m] = Wt + (size_t)(vb + cl) * H_ + (pcB ^ ((cl >> 1) & 3)) * 8;
    }

    f32x4 acc[4][4];
    #pragma unroll
    for (int i = 0; i < 4; ++i)
        #pragma unroll
        for (int j = 0; j < 4; ++j)
            acc[i][j] = (f32x4){0.f, 0.f, 0.f, 0.f};

    {
        uint4 E = *(const uint4*)(eR);
        uint4 D = *(const uint4*)(dR);
        uint4 x;
        x.x = addrelu_pk(E.x, D.x); x.y = addrelu_pk(E.y, D.y);
        x.z = addrelu_pk(E.z, D.z); x.w = addrelu_pk(E.w, D.w);
        LA[0][r][kc ^ fA] = x;
        #pragma unroll
        for (int m = 0; m < 4; ++m)
            gload_lds16(gB[m], &LB[0][w * 64 + m * 16][0]);
    }
    __syncthreads();

    #pragma unroll 2
    for (int kt = 0; kt < 20; ++kt) {
        int cur = kt & 1;
        uint4 En, Dn;
        if (kt < 19) {
            En = *(const uint4*)(eR + (kt + 1) * 32);
            Dn = *(const uint4*)(dR + (kt + 1) * 32);
            #pragma unroll
            for (int m = 0; m < 4; ++m)
                gload_lds16(gB[m] + (kt + 1) * 32, &LB[cur ^ 1][w * 64 + m * 16][0]);
        }
        bf16x8 a[4], bq[4];
        #pragma unroll
        for (int i = 0; i < 4; ++i) {
            int row = i * 16 + lrow;
            a[i] = __builtin_bit_cast(bf16x8, LA[cur][row][kg ^ ((row >> 1) & 3)]);
        }
        #pragma unroll
        for (int j = 0; j < 4; ++j) {
            int col = w * 64 + j * 16 + lrow;
            bq[j] = __builtin_bit_cast(bf16x8, LB[cur][col][kg ^ ((col >> 1) & 3)]);
        }
        #pragma unroll
        for (int i = 0; i < 4; ++i)
            #pragma unroll
            for (int j = 0; j < 4; ++j)
                acc[i][j] = __builtin_amdgcn_mfma_f32_16x16x32_bf16(a[i], bq[j], acc[i][j], 0, 0, 0);
        if (kt < 19) {
            uint4 x;
            x.x = addrelu_pk(En.x, Dn.x); x.y = addrelu_pk(En.y, Dn.y);
            x.z = addrelu_pk(En.z, Dn.z); x.w = addrelu_pk(En.w, Dn.w);
            LA[cur ^ 1][r][kc ^ fA] = x;
        }
        __syncthreads();
    }

    // ---- epilogue: acc -> LDS [16][ESTR] -> scalar dword stores, 256B/instr contiguous
    float* etile = (float*)LB;                  // 16*260*4 = 16.6 KB (aliases LB, K-loop done)
    #pragma unroll 1
    for (int i = 0; i < 4; ++i) {
        __syncthreads();
        #pragma unroll
        for (int j = 0; j < 4; ++j) {
            int col = w * 64 + j * 16 + lrow;
            float bo = b_out[vb + col];
            #pragma unroll
            for (int q = 0; q < 4; ++q)
                etile[(kg * 4 + q) * ESTR + col] = acc[i][j][q] + bo;
        }
        __syncthreads();
        // wave w stores rows w*4..w*4+3; per row: 4 instrs x (64 lanes x 4B contiguous)
        #pragma unroll
        for (int rr = 0; rr < 4; ++rr) {
            int row16 = w * 4 + rr;
            int row = i * 16 + row16;
            int t = t0 + (row >> 3);
            int u = u0 + (row & 7);
            if (u < U_) {
                float* ob = &out[(((size_t)b * T_ + t) * U_ + u) * V_ + vb];
                const float* lb = &etile[row16 * ESTR];
                #pragma unroll
                for (int it = 0; it < 4; ++it)
                    ob[it * 64 + lane] = lb[it * 64 + lane];
            }
        }
    }
}

extern "C" void kernel_launch(void* const* d_in, const int* in_sizes, int n_in,
                              void* d_out, int out_size, void* d_ws, size_t ws_size,
                              hipStream_t stream) {
    const float* enc    = (const float*)d_in[0];
    const float* dec    = (const float*)d_in[1];
    const float* W_enc  = (const float*)d_in[2];
    const float* b_enc  = (const float*)d_in[3];
    const float* W_pred = (const float*)d_in[4];
    const float* b_pred = (const float*)d_in[5];
    const float* W_out  = (const float*)d_in[6];
    const float* b_out  = (const float*)d_in[7];
    float* out = (float*)d_out;

    char* ws = (char*)d_ws;
    __hip_bfloat16* encP = (__hip_bfloat16*)ws;                       // 1,024,000 B
    __hip_bfloat16* decP = (__hip_bfloat16*)(ws + 1024000);           //   512,000 B
    unsigned short* Wt   = (unsigned short*)(ws + 1024000 + 512000);  // 1,474,560 B

    prep_fused_kernel<<<dim3(700), 256, 0, stream>>>(
        enc, W_enc, b_enc, dec, W_pred, b_pred, W_out, encP, decP, Wt);
    joint_kernel<<<dim3(5200 + (B_ * T_ * U_ + 255) / 256), 256, 0, stream>>>(
        (const unsigned short*)encP, (const unsigned short*)decP, Wt, b_out, out);
}

// Round 17
// 273.304 us; speedup vs baseline: 4.0175x; 4.0175x over previous
//
#include <hip/hip_runtime.h>
#include <hip/hip_bf16.h>

#define B_   4
#define DENC 512
#define T_   200
#define DDEC 640
#define U_   100
#define H_   640
#define V_   1025
#define VPAD 1152

typedef float f32x4 __attribute__((ext_vector_type(4)));
typedef __bf16 bf16x8 __attribute__((ext_vector_type(8)));
typedef unsigned short u16x8 __attribute__((ext_vector_type(8)));

__device__ __forceinline__ float bf2f(unsigned short s) {
    return __uint_as_float(((unsigned)s) << 16);
}

__device__ __forceinline__ unsigned addrelu_pk(unsigned e, unsigned d) {
    float elo = __uint_as_float(e << 16);
    float ehi = __uint_as_float(e & 0xffff0000u);
    float dlo = __uint_as_float(d << 16);
    float dhi = __uint_as_float(d & 0xffff0000u);
    float lo = fmaxf(elo + dlo, 0.f);
    float hi = fmaxf(ehi + dhi, 0.f);
    unsigned r;
    asm("v_cvt_pk_bf16_f32 %0, %1, %2" : "=v"(r) : "v"(lo), "v"(hi));
    return r;
}

__device__ __forceinline__ void gload_lds16(const void* g, void* l) {
    __builtin_amdgcn_global_load_lds(
        (const __attribute__((address_space(1))) unsigned int*)g,
        (__attribute__((address_space(3))) unsigned int*)l, 16, 0, 0);
}

// ---------------- K1: fused prep (r13-proven): enc_proj | dec_proj | wt_transpose
__global__ __launch_bounds__(256) void prep_fused_kernel(
    const float* __restrict__ enc, const float* __restrict__ W_enc,
    const float* __restrict__ b_enc,
    const float* __restrict__ dec, const float* __restrict__ W_pred,
    const float* __restrict__ b_pred,
    const float* __restrict__ W_out,
    __hip_bfloat16* __restrict__ encP, __hip_bfloat16* __restrict__ decP,
    unsigned short* __restrict__ Wt)
{
    __shared__ float tile[64][65];
    int bx = blockIdx.x;
    int tid = threadIdx.x;

    if (bx < 260) {
        int b = bx / 65, r5 = bx % 65, hc = r5 / 13, tg = r5 % 13;
        int h  = hc * 128 + (tid & 127);
        int t0 = tg * 16 + (tid >> 7) * 8;
        if (t0 >= T_) return;
        const float* ec = enc + (size_t)b * DENC * T_ + t0;
        const float* Wc = W_enc + h;
        float acc[8] = {0.f,0.f,0.f,0.f,0.f,0.f,0.f,0.f};
        #pragma unroll 8
        for (int d = 0; d < DENC; ++d) {
            float w = Wc[(size_t)d * H_];
            float4 e0 = *(const float4*)(ec + (size_t)d * T_);
            float4 e1 = *(const float4*)(ec + (size_t)d * T_ + 4);
            acc[0] += w * e0.x; acc[1] += w * e0.y; acc[2] += w * e0.z; acc[3] += w * e0.w;
            acc[4] += w * e1.x; acc[5] += w * e1.y; acc[6] += w * e1.z; acc[7] += w * e1.w;
        }
        float bb = b_enc[h];
        #pragma unroll
        for (int i = 0; i < 8; ++i)
            encP[((size_t)b * T_ + t0 + i) * H_ + h] = __float2bfloat16(acc[i] + bb);
    } else if (bx < 520) {
        int i5 = bx - 260;
        int b = i5 / 65, r5 = i5 % 65, hc = r5 / 13, ug = r5 % 13;
        int h  = hc * 128 + (tid & 127);
        int u0 = ug * 8 + (tid >> 7) * 4;
        if (u0 >= U_) return;
        const float* dc = dec + (size_t)b * DDEC * U_ + u0;
        const float* Wc = W_pred + h;
        float acc[4] = {0.f,0.f,0.f,0.f};
        #pragma unroll 8
        for (int d = 0; d < DDEC; ++d) {
            float w = Wc[(size_t)d * H_];
            float4 e0 = *(const float4*)(dc + (size_t)d * U_);
            acc[0] += w * e0.x; acc[1] += w * e0.y; acc[2] += w * e0.z; acc[3] += w * e0.w;
        }
        float bb = b_pred[h];
        #pragma unroll
        for (int i = 0; i < 4; ++i)
            decP[((size_t)b * U_ + u0 + i) * H_ + h] = __float2bfloat16(acc[i] + bb);
    } else {
        int j = bx - 520;
        int hc = j / 18, vc = j % 18;
        int h0 = hc * 64, v0 = vc * 64;
        #pragma unroll
        for (int it = 0; it < 16; ++it) {
            int hl = it * 4 + (tid >> 6);
            int vl = tid & 63;
            int v = v0 + vl;
            tile[hl][vl] = (v < V_) ? W_out[(size_t)(h0 + hl) * V_ + v] : 0.f;
        }
        __syncthreads();
        #pragma unroll
        for (int it = 0; it < 16; ++it) {
            int vl = it * 4 + (tid >> 6);
            int hl = tid & 63;
            __bf16 bv = (__bf16)tile[hl][vl];
            Wt[(size_t)(v0 + vl) * H_ + h0 + hl] = *(unsigned short*)&bv;
        }
    }
}

// ---------------- K4: r8-proven joint + LDS-transpose epilogue (FULLY UNROLLED —
// rule #20: runtime acc index in r15/r16 spilled acc to scratch = 6GB HBM writes).
// blocks [0,5200): GEMM tiles (XCD-swizzled).  blocks [5200,5513): v=1024 column.
#define ESTR 260   // epilogue LDS stride (f32): 2 lanes/bank both phases (free)
__global__ __launch_bounds__(256) void joint_kernel(
    const unsigned short* __restrict__ encP,   // [B,T,H] bf16
    const unsigned short* __restrict__ decP,   // [B,U,H] bf16
    const unsigned short* __restrict__ Wt,     // [VPAD][H] bf16
    const float* __restrict__ b_out,           // [V]
    float* __restrict__ out)                   // [B,T,U,V] f32
{
    __shared__ uint4 LA[2][64][4];             // 8 KB
    __shared__ uint4 LB[2][256][4];            // 32 KB
    int tid = threadIdx.x;

    if (blockIdx.x >= 5200) {
        // ---- fused lastcol: v = 1024
        int idx = (blockIdx.x - 5200) * 256 + tid;
        if (idx >= B_ * T_ * U_) return;
        int u = idx % U_;
        int t = (idx / U_) % T_;
        int b = idx / (U_ * T_);
        const u16x8* e = (const u16x8*)(encP + ((size_t)b * T_ + t) * H_);
        const u16x8* d = (const u16x8*)(decP + ((size_t)b * U_ + u) * H_);
        const u16x8* wv = (const u16x8*)(Wt + (size_t)1024 * H_);
        float acc1 = 0.f;
        for (int c = 0; c < H_ / 8; ++c) {
            u16x8 ev = e[c], dv = d[c], wq = wv[c];
            #pragma unroll
            for (int m = 0; m < 8; ++m)
                acc1 += fmaxf(bf2f(ev[m]) + bf2f(dv[m]), 0.f) * bf2f(wq[m]);
        }
        out[((size_t)(b * T_ + t) * U_ + u) * V_ + 1024] = acc1 + b_out[1024];
        return;
    }

    // ---- XCD swizzle over the 5200 GEMM blocks: f -> n = (f&7)*650 + (f>>3)
    int f   = blockIdx.x;
    int n   = (f & 7) * 650 + (f >> 3);
    int vi  = n / 1300;
    int rem = n - vi * 1300;
    int b   = rem / 325;
    int tu  = rem - b * 325;

    int tt = tu / 13, ut = tu % 13;
    int t0 = tt * 8, u0 = ut * 8, vb = vi * 256;
    int lane = tid & 63, w = tid >> 6;
    int lrow = lane & 15, kg = lane >> 4;

    int r  = tid >> 2, kc = tid & 3;
    int ta = t0 + (r >> 3);
    int ua = u0 + (r & 7); if (ua > U_ - 1) ua = U_ - 1;
    const unsigned short* eR = encP + ((size_t)b * T_ + ta) * H_ + kc * 8;
    const unsigned short* dR = decP + ((size_t)b * U_ + ua) * H_ + kc * 8;
    int fA = (r >> 1) & 3;

    int pcB = lane & 3;
    const unsigned short* gB[4];
    #pragma unroll
    for (int m = 0; m < 4; ++m) {
        int cl = w * 64 + m * 16 + (lane >> 2);
        gB[m] = Wt + (size_t)(vb + cl) * H_ + (pcB ^ ((cl >> 1) & 3)) * 8;
    }

    f32x4 acc[4][4];
    #pragma unroll
    for (int i = 0; i < 4; ++i)
        #pragma unroll
        for (int j = 0; j < 4; ++j)
            acc[i][j] = (f32x4){0.f, 0.f, 0.f, 0.f};

    {
        uint4 E = *(const uint4*)(eR);
        uint4 D = *(const uint4*)(dR);
        uint4 x;
        x.x = addrelu_pk(E.x, D.x); x.y = addrelu_pk(E.y, D.y);
        x.z = addrelu_pk(E.z, D.z); x.w = addrelu_pk(E.w, D.w);
        LA[0][r][kc ^ fA] = x;
        #pragma unroll
        for (int m = 0; m < 4; ++m)
            gload_lds16(gB[m], &LB[0][w * 64 + m * 16][0]);
    }
    __syncthreads();

    #pragma unroll 2
    for (int kt = 0; kt < 20; ++kt) {
        int cur = kt & 1;
        uint4 En, Dn;
        if (kt < 19) {
            En = *(const uint4*)(eR + (kt + 1) * 32);
            Dn = *(const uint4*)(dR + (kt + 1) * 32);
            #pragma unroll
            for (int m = 0; m < 4; ++m)
                gload_lds16(gB[m] + (kt + 1) * 32, &LB[cur ^ 1][w * 64 + m * 16][0]);
        }
        bf16x8 a[4], bq[4];
        #pragma unroll
        for (int i = 0; i < 4; ++i) {
            int row = i * 16 + lrow;
            a[i] = __builtin_bit_cast(bf16x8, LA[cur][row][kg ^ ((row >> 1) & 3)]);
        }
        #pragma unroll
        for (int j = 0; j < 4; ++j) {
            int col = w * 64 + j * 16 + lrow;
            bq[j] = __builtin_bit_cast(bf16x8, LB[cur][col][kg ^ ((col >> 1) & 3)]);
        }
        #pragma unroll
        for (int i = 0; i < 4; ++i)
            #pragma unroll
            for (int j = 0; j < 4; ++j)
                acc[i][j] = __builtin_amdgcn_mfma_f32_16x16x32_bf16(a[i], bq[j], acc[i][j], 0, 0, 0);
        if (kt < 19) {
            uint4 x;
            x.x = addrelu_pk(En.x, Dn.x); x.y = addrelu_pk(En.y, Dn.y);
            x.z = addrelu_pk(En.z, Dn.z); x.w = addrelu_pk(En.w, Dn.w);
            LA[cur ^ 1][r][kc ^ fA] = x;
        }
        __syncthreads();
    }

    // ---- epilogue: acc -> LDS [16][ESTR] -> scalar stores, 256B/instr contiguous.
    // FULLY unrolled: every acc[i][j][q] index is compile-time (rule #20).
    float* etile = (float*)LB;                  // 16*260*4 = 16.6 KB (aliases LB; K-loop done)
    #pragma unroll
    for (int i = 0; i < 4; ++i) {
        __syncthreads();
        #pragma unroll
        for (int j = 0; j < 4; ++j) {
            int col = w * 64 + j * 16 + lrow;
            float bo = b_out[vb + col];
            #pragma unroll
            for (int q = 0; q < 4; ++q)
                etile[(kg * 4 + q) * ESTR + col] = acc[i][j][q] + bo;
        }
        __syncthreads();
        // wave w stores rows w*4..w*4+3; per row: 4 instrs x (64 lanes x 4B contiguous)
        #pragma unroll
        for (int rr = 0; rr < 4; ++rr) {
            int row16 = w * 4 + rr;
            int row = i * 16 + row16;
            int t = t0 + (row >> 3);
            int u = u0 + (row & 7);
            if (u < U_) {
                float* ob = &out[(((size_t)b * T_ + t) * U_ + u) * V_ + vb];
                const float* lb = &etile[row16 * ESTR];
                #pragma unroll
                for (int it = 0; it < 4; ++it)
                    ob[it * 64 + lane] = lb[it * 64 + lane];
            }
        }
    }
}

extern "C" void kernel_launch(void* const* d_in, const int* in_sizes, int n_in,
                              void* d_out, int out_size, void* d_ws, size_t ws_size,
                              hipStream_t stream) {
    const float* enc    = (const float*)d_in[0];
    const float* dec    = (const float*)d_in[1];
    const float* W_enc  = (const float*)d_in[2];
    const float* b_enc  = (const float*)d_in[3];
    const float* W_pred = (const float*)d_in[4];
    const float* b_pred = (const float*)d_in[5];
    const float* W_out  = (const float*)d_in[6];
    const float* b_out  = (const float*)d_in[7];
    float* out = (float*)d_out;

    char* ws = (char*)d_ws;
    __hip_bfloat16* encP = (__hip_bfloat16*)ws;                       // 1,024,000 B
    __hip_bfloat16* decP = (__hip_bfloat16*)(ws + 1024000);           //   512,000 B
    unsigned short* Wt   = (unsigned short*)(ws + 1024000 + 512000);  // 1,474,560 B

    prep_fused_kernel<<<dim3(700), 256, 0, stream>>>(
        enc, W_enc, b_enc, dec, W_pred, b_pred, W_out, encP, decP, Wt);
    joint_kernel<<<dim3(5200 + (B_ * T_ * U_ + 255) / 256), 256, 0, stream>>>(
        (const unsigned short*)encP, (const unsigned short*)decP, Wt, b_out, out);
}

// Round 18
// 272.723 us; speedup vs baseline: 4.0260x; 1.0021x over previous
//
#include <hip/hip_runtime.h>
#include <hip/hip_bf16.h>

#define B_   4
#define DENC 512
#define T_   200
#define DDEC 640
#define U_   100
#define H_   640
#define V_   1025
#define VPAD 1152

typedef float f32x4 __attribute__((ext_vector_type(4)));
typedef _Float16 f16x8 __attribute__((ext_vector_type(8)));
typedef unsigned short u16x8 __attribute__((ext_vector_type(8)));

// relu(e+d) on 8 packed fp16: 4x v_pk_add_f16 + 4x v_pk_max_f16
__device__ __forceinline__ uint4 addrelu16(uint4 e, uint4 d) {
    f16x8 ev = __builtin_bit_cast(f16x8, e);
    f16x8 dv = __builtin_bit_cast(f16x8, d);
    f16x8 s = ev + dv;
    f16x8 z = {(_Float16)0.f, (_Float16)0.f, (_Float16)0.f, (_Float16)0.f,
               (_Float16)0.f, (_Float16)0.f, (_Float16)0.f, (_Float16)0.f};
    s = __builtin_elementwise_max(s, z);
    return __builtin_bit_cast(uint4, s);
}

__device__ __forceinline__ void gload_lds16(const void* g, void* l) {
    __builtin_amdgcn_global_load_lds(
        (const __attribute__((address_space(1))) unsigned int*)g,
        (__attribute__((address_space(3))) unsigned int*)l, 16, 0, 0);
}

// ---------------- K1: fused prep (r13-proven structure), fp16 outputs
__global__ __launch_bounds__(256) void prep_fused_kernel(
    const float* __restrict__ enc, const float* __restrict__ W_enc,
    const float* __restrict__ b_enc,
    const float* __restrict__ dec, const float* __restrict__ W_pred,
    const float* __restrict__ b_pred,
    const float* __restrict__ W_out,
    _Float16* __restrict__ encP, _Float16* __restrict__ decP,
    _Float16* __restrict__ Wt)
{
    __shared__ float tile[64][65];
    int bx = blockIdx.x;
    int tid = threadIdx.x;

    if (bx < 260) {
        int b = bx / 65, r5 = bx % 65, hc = r5 / 13, tg = r5 % 13;
        int h  = hc * 128 + (tid & 127);
        int t0 = tg * 16 + (tid >> 7) * 8;
        if (t0 >= T_) return;
        const float* ec = enc + (size_t)b * DENC * T_ + t0;
        const float* Wc = W_enc + h;
        float acc[8] = {0.f,0.f,0.f,0.f,0.f,0.f,0.f,0.f};
        #pragma unroll 8
        for (int d = 0; d < DENC; ++d) {
            float w = Wc[(size_t)d * H_];
            float4 e0 = *(const float4*)(ec + (size_t)d * T_);
            float4 e1 = *(const float4*)(ec + (size_t)d * T_ + 4);
            acc[0] += w * e0.x; acc[1] += w * e0.y; acc[2] += w * e0.z; acc[3] += w * e0.w;
            acc[4] += w * e1.x; acc[5] += w * e1.y; acc[6] += w * e1.z; acc[7] += w * e1.w;
        }
        float bb = b_enc[h];
        #pragma unroll
        for (int i = 0; i < 8; ++i)
            encP[((size_t)b * T_ + t0 + i) * H_ + h] = (_Float16)(acc[i] + bb);
    } else if (bx < 520) {
        int i5 = bx - 260;
        int b = i5 / 65, r5 = i5 % 65, hc = r5 / 13, ug = r5 % 13;
        int h  = hc * 128 + (tid & 127);
        int u0 = ug * 8 + (tid >> 7) * 4;
        if (u0 >= U_) return;
        const float* dc = dec + (size_t)b * DDEC * U_ + u0;
        const float* Wc = W_pred + h;
        float acc[4] = {0.f,0.f,0.f,0.f};
        #pragma unroll 8
        for (int d = 0; d < DDEC; ++d) {
            float w = Wc[(size_t)d * H_];
            float4 e0 = *(const float4*)(dc + (size_t)d * U_);
            acc[0] += w * e0.x; acc[1] += w * e0.y; acc[2] += w * e0.z; acc[3] += w * e0.w;
        }
        float bb = b_pred[h];
        #pragma unroll
        for (int i = 0; i < 4; ++i)
            decP[((size_t)b * U_ + u0 + i) * H_ + h] = (_Float16)(acc[i] + bb);
    } else {
        int j = bx - 520;
        int hc = j / 18, vc = j % 18;
        int h0 = hc * 64, v0 = vc * 64;
        #pragma unroll
        for (int it = 0; it < 16; ++it) {
            int hl = it * 4 + (tid >> 6);
            int vl = tid & 63;
            int v = v0 + vl;
            tile[hl][vl] = (v < V_) ? W_out[(size_t)(h0 + hl) * V_ + v] : 0.f;
        }
        __syncthreads();
        #pragma unroll
        for (int it = 0; it < 16; ++it) {
            int vl = it * 4 + (tid >> 6);
            int hl = tid & 63;
            Wt[(size_t)(v0 + vl) * H_ + h0 + hl] = (_Float16)tile[hl][vl];
        }
    }
}

// ---------------- K4: r17-proven joint, fp16 operands (same structure/swizzles/epilogue)
// blocks [0,5200): GEMM tiles (XCD-swizzled).  blocks [5200,5513): v=1024 column.
#define ESTR 260
__global__ __launch_bounds__(256) void joint_kernel(
    const unsigned short* __restrict__ encP,   // [B,T,H] fp16
    const unsigned short* __restrict__ decP,   // [B,U,H] fp16
    const unsigned short* __restrict__ Wt,     // [VPAD][H] fp16
    const float* __restrict__ b_out,           // [V]
    float* __restrict__ out)                   // [B,T,U,V] f32
{
    __shared__ uint4 LA[2][64][4];             // 8 KB
    __shared__ uint4 LB[2][256][4];            // 32 KB
    int tid = threadIdx.x;

    if (blockIdx.x >= 5200) {
        // ---- fused lastcol: v = 1024
        int idx = (blockIdx.x - 5200) * 256 + tid;
        if (idx >= B_ * T_ * U_) return;
        int u = idx % U_;
        int t = (idx / U_) % T_;
        int b = idx / (U_ * T_);
        const uint4* e = (const uint4*)(encP + ((size_t)b * T_ + t) * H_);
        const uint4* d = (const uint4*)(decP + ((size_t)b * U_ + u) * H_);
        const uint4* wv = (const uint4*)(Wt + (size_t)1024 * H_);
        float acc1 = 0.f;
        for (int c = 0; c < H_ / 8; ++c) {
            f16x8 x = __builtin_bit_cast(f16x8, addrelu16(e[c], d[c]));
            f16x8 wq = __builtin_bit_cast(f16x8, wv[c]);
            #pragma unroll
            for (int m = 0; m < 8; ++m)
                acc1 += (float)x[m] * (float)wq[m];
        }
        out[((size_t)(b * T_ + t) * U_ + u) * V_ + 1024] = acc1 + b_out[1024];
        return;
    }

    // ---- XCD swizzle over the 5200 GEMM blocks: f -> n = (f&7)*650 + (f>>3)
    int f   = blockIdx.x;
    int n   = (f & 7) * 650 + (f >> 3);
    int vi  = n / 1300;
    int rem = n - vi * 1300;
    int b   = rem / 325;
    int tu  = rem - b * 325;

    int tt = tu / 13, ut = tu % 13;
    int t0 = tt * 8, u0 = ut * 8, vb = vi * 256;
    int lane = tid & 63, w = tid >> 6;
    int lrow = lane & 15, kg = lane >> 4;

    int r  = tid >> 2, kc = tid & 3;
    int ta = t0 + (r >> 3);
    int ua = u0 + (r & 7); if (ua > U_ - 1) ua = U_ - 1;
    const unsigned short* eR = encP + ((size_t)b * T_ + ta) * H_ + kc * 8;
    const unsigned short* dR = decP + ((size_t)b * U_ + ua) * H_ + kc * 8;
    int fA = (r >> 1) & 3;

    int pcB = lane & 3;
    const unsigned short* gB[4];
    #pragma unroll
    for (int m = 0; m < 4; ++m) {
        int cl = w * 64 + m * 16 + (lane >> 2);
        gB[m] = Wt + (size_t)(vb + cl) * H_ + (pcB ^ ((cl >> 1) & 3)) * 8;
    }

    f32x4 acc[4][4];
    #pragma unroll
    for (int i = 0; i < 4; ++i)
        #pragma unroll
        for (int j = 0; j < 4; ++j)
            acc[i][j] = (f32x4){0.f, 0.f, 0.f, 0.f};

    {
        uint4 E = *(const uint4*)(eR);
        uint4 D = *(const uint4*)(dR);
        LA[0][r][kc ^ fA] = addrelu16(E, D);
        #pragma unroll
        for (int m = 0; m < 4; ++m)
            gload_lds16(gB[m], &LB[0][w * 64 + m * 16][0]);
    }
    __syncthreads();

    #pragma unroll 2
    for (int kt = 0; kt < 20; ++kt) {
        int cur = kt & 1;
        uint4 En, Dn;
        if (kt < 19) {
            En = *(const uint4*)(eR + (kt + 1) * 32);
            Dn = *(const uint4*)(dR + (kt + 1) * 32);
            #pragma unroll
            for (int m = 0; m < 4; ++m)
                gload_lds16(gB[m] + (kt + 1) * 32, &LB[cur ^ 1][w * 64 + m * 16][0]);
        }
        f16x8 a[4], bq[4];
        #pragma unroll
        for (int i = 0; i < 4; ++i) {
            int row = i * 16 + lrow;
            a[i] = __builtin_bit_cast(f16x8, LA[cur][row][kg ^ ((row >> 1) & 3)]);
        }
        #pragma unroll
        for (int j = 0; j < 4; ++j) {
            int col = w * 64 + j * 16 + lrow;
            bq[j] = __builtin_bit_cast(f16x8, LB[cur][col][kg ^ ((col >> 1) & 3)]);
        }
        #pragma unroll
        for (int i = 0; i < 4; ++i)
            #pragma unroll
            for (int j = 0; j < 4; ++j)
                acc[i][j] = __builtin_amdgcn_mfma_f32_16x16x32_f16(a[i], bq[j], acc[i][j], 0, 0, 0);
        if (kt < 19)
            LA[cur ^ 1][r][kc ^ fA] = addrelu16(En, Dn);
        __syncthreads();
    }

    // ---- epilogue (r17-proven): acc -> LDS [16][ESTR] -> 256B-contiguous scalar stores
    float* etile = (float*)LB;
    #pragma unroll
    for (int i = 0; i < 4; ++i) {
        __syncthreads();
        #pragma unroll
        for (int j = 0; j < 4; ++j) {
            int col = w * 64 + j * 16 + lrow;
            float bo = b_out[vb + col];
            #pragma unroll
            for (int q = 0; q < 4; ++q)
                etile[(kg * 4 + q) * ESTR + col] = acc[i][j][q] + bo;
        }
        __syncthreads();
        #pragma unroll
        for (int rr = 0; rr < 4; ++rr) {
            int row16 = w * 4 + rr;
            int row = i * 16 + row16;
            int t = t0 + (row >> 3);
            int u = u0 + (row & 7);
            if (u < U_) {
                float* ob = &out[(((size_t)b * T_ + t) * U_ + u) * V_ + vb];
                const float* lb = &etile[row16 * ESTR];
                #pragma unroll
                for (int it = 0; it < 4; ++it)
                    ob[it * 64 + lane] = lb[it * 64 + lane];
            }
        }
    }
}

extern "C" void kernel_launch(void* const* d_in, const int* in_sizes, int n_in,
                              void* d_out, int out_size, void* d_ws, size_t ws_size,
                              hipStream_t stream) {
    const float* enc    = (const float*)d_in[0];
    const float* dec    = (const float*)d_in[1];
    const float* W_enc  = (const float*)d_in[2];
    const float* b_enc  = (const float*)d_in[3];
    const float* W_pred = (const float*)d_in[4];
    const float* b_pred = (const float*)d_in[5];
    const float* W_out  = (const float*)d_in[6];
    const float* b_out  = (const float*)d_in[7];
    float* out = (float*)d_out;

    // fp16 buffers: 4*200*640 = 512,000 elems = 1,024,000 B (NOT 512,000 B — the r6/r7 bug)
    char* ws = (char*)d_ws;
    _Float16* encP = (_Float16*)ws;                        // 1,024,000 B
    _Float16* decP = (_Float16*)(ws + 1024000);            //   512,000 B
    _Float16* Wt   = (_Float16*)(ws + 1024000 + 512000);   // 1,474,560 B

    prep_fused_kernel<<<dim3(700), 256, 0, stream>>>(
        enc, W_enc, b_enc, dec, W_pred, b_pred, W_out, encP, decP, Wt);
    joint_kernel<<<dim3(5200 + (B_ * T_ * U_ + 255) / 256), 256, 0, stream>>>(
        (const unsigned short*)encP, (const unsigned short*)decP,
        (const unsigned short*)Wt, b_out, out);
}